// Round 20
// baseline (134.719 us; speedup 1.0000x reference)
//
#include <hip/hip_runtime.h>
#include <hip/hip_bf16.h>

// ---------------------------------------------------------------------------
// LayerNormGRUCell: B=16384, I=H=512
//   G = [x@W_i2h.T | h@W_h2h.T | x@W_hatW.T | h@W_hatU.T]  (16384 x 3072)
//   then per-row: LN segments + gates + tanh + lerp -> h_t (16384 x 512 fp32)
// ws layout (bf16 elements):
//   Wcat @ 0        (3072*512)    rows: [W_i2h;W_h2h;W_hatW;W_hatU]
//   Gb   @ 1572864  (16384*3072)
// Round-20: panels 1-5 go BARRIER-FREE: B fragments read directly from
// L2-resident W into registers (per-wave, 16 full 64B lines per load -> 
// coalesced), A from the resident LDS tile, register double-buffering
// (aN/bN prefetched mid-MFMA, compiler-counted waits). No vmcnt(0) drains,
// no s_barrier, no lockstep -- waves free-run (T5 regime).
// Panel 0 (A-streaming + B via LDS) / convert_w / ln_gate = r19 verbatim.
// ---------------------------------------------------------------------------

using f32x4 = __attribute__((ext_vector_type(4))) float;
using s16x8 = __attribute__((ext_vector_type(8))) short;
typedef __attribute__((ext_vector_type(8))) unsigned short u16x8;

#define WB_OFF   0ull
#define GB_OFF   1572864ull

__device__ __forceinline__ void async_load16(const void* g, void* l) {
  __builtin_amdgcn_global_load_lds(
      (const __attribute__((address_space(1))) unsigned int*)g,
      (__attribute__((address_space(3))) unsigned int*)l, 16, 0, 0);
}

__device__ __forceinline__ float bfraw2f(unsigned short u) {
  union { unsigned int i; float f; } c;
  c.i = ((unsigned int)u) << 16;
  return c.f;
}

// -------------------------- fp32 -> bf16 weights only ----------------------
__global__ __launch_bounds__(256) void convert_w_kernel(
    const float* __restrict__ w0, const float* __restrict__ w1,
    const float* __restrict__ w2, const float* __restrict__ w3,
    __hip_bfloat16* __restrict__ dst)
{
  const size_t i = (size_t)blockIdx.x * 256 + threadIdx.x;  // vec4 index
  const float* src;
  __hip_bfloat16* d;
  size_t o;
  if (i < 131072ull)      { src = w0; d = dst;            o = i; }
  else if (i < 262144ull) { src = w1; d = dst + 524288;   o = i - 131072ull; }
  else if (i < 327680ull) { src = w2; d = dst + 1048576;  o = i - 262144ull; }
  else                    { src = w3; d = dst + 1310720;  o = i - 327680ull; }
  const float4 v = *(const float4*)(src + 4 * o);
  __hip_bfloat16 t4[4] = {__float2bfloat16(v.x), __float2bfloat16(v.y),
                          __float2bfloat16(v.z), __float2bfloat16(v.w)};
  *(uint2*)(d + 4 * o) = *(const uint2*)t4;
}

// -------------------------------- GEMM -------------------------------------
// 256 blocks x 512 threads, 1 block/CU. type=bid&1 (0=X,1=H), mband=bid>>1.
// X n-tiles {0,1,2,3,8,9}; H {4,5,6,7,10,11}. W panels L2-resident per XCD.
// LDS: A resident [kt=16][128 rows][64 B] (131072 B) + B ring-2 (32768 B,
// used by panel 0 only). Panel 0 streams A fp32->bf16 (r17/r18 schedule).
// Panels 1-5: A frags from LDS, B frags DIRECT FROM GLOBAL (L2) to regs;
// barrier-free, register-dbuf'd; compiler inserts counted vmcnt/lgkm.

#define B_BASE 131072

__device__ __forceinline__ void stage_B(const char* base, char* slot,
                                        int koff, int wave, int lane) {
#pragma unroll
  for (int i = 0; i < 2; ++i) {
    const int c = wave * 2 + i;
    const int row  = c * 16 + (lane >> 2);
    const int colb = ((lane & 3) * 16) ^ (((lane >> 3) & 3) << 4);  // pre-swz
    async_load16(base + (size_t)row * 1024 + koff + colb,
                 slot + c * 1024 + lane * 16);
  }
}

__device__ __forceinline__ void cvt_write8(void* dst, const float4& f0,
                                           const float4& f1) {
  union { s16x8 v; __hip_bfloat16 b[8]; } u;
  u.b[0] = __float2bfloat16(f0.x); u.b[1] = __float2bfloat16(f0.y);
  u.b[2] = __float2bfloat16(f0.z); u.b[3] = __float2bfloat16(f0.w);
  u.b[4] = __float2bfloat16(f1.x); u.b[5] = __float2bfloat16(f1.y);
  u.b[6] = __float2bfloat16(f1.z); u.b[7] = __float2bfloat16(f1.w);
  *(s16x8*)dst = u.v;
}

__global__ __launch_bounds__(512, 2) void gemm_kernel(
    const float* __restrict__ xf,
    const float* __restrict__ hf,
    const __hip_bfloat16* __restrict__ Wb,
    __hip_bfloat16* __restrict__ G)
{
  const int bid   = blockIdx.x;     // 256
  const int type  = bid & 1;        // 0 = X, 1 = H
  const int mband = bid >> 1;       // 0..127
  const int m0    = mband * 128;
  const float* Af = (type ? hf : xf) + (size_t)m0 * 512;

  __shared__ __align__(16) char lds[163840];

  const int tid  = threadIdx.x;
  const int lane = tid & 63;
  const int wave = tid >> 6;
  const int wm = wave >> 2, wn = wave & 3;   // 2 x 4 wave grid, 64x64 each

  const int lk  = (lane >> 4) * 16;
  const int lr  = lane & 15;
  const int rdk = lk ^ (((lr >> 1) & 3) << 4);     // read swizzle (A and B)

  auto rdA = [&](int kt, int fm) {
    return *(const s16x8*)(lds + kt * 8192 +
                           (wm * 64 + fm * 16 + lr) * 64 + rdk);
  };
  auto rdB = [&](int slot, int fn) {
    return *(const s16x8*)(lds + B_BASE + slot * 16384 +
                           (wn * 64 + fn * 16 + lr) * 64 + rdk);
  };

  const int ntl0 = type ? 4 : 0;
  const char* Bb0 = (const char*)Wb + (size_t)ntl0 * 256 * 1024;

  stage_B(Bb0, lds + B_BASE, 0, wave, lane);

  const int arow = tid >> 2;                         // 0..127
  const int alin = (tid & 3) * 16;                   // linear byte pos
  const int acb  = alin ^ (((arow >> 1) & 3) << 4);  // swizzled LDS pos
  const float* abase = Af + (size_t)arow * 512 + (alin >> 1);
  char* const awr = lds + arow * 64 + acb;           // + kt*8192

  float4 hA, hB;
  {
    const float4 a0 = *(const float4*)(abase);       // A(0)
    const float4 a1 = *(const float4*)(abase + 4);
    hA = *(const float4*)(abase + 32);               // A(1)
    hB = *(const float4*)(abase + 36);
    cvt_write8(awr, a0, a1);                         // write A(0)
  }

  // ---- panel 0: compute ntl0 while streaming A into residence (r18) ----
  {
    f32x4 acc[4][4];
#pragma unroll
    for (int a = 0; a < 4; ++a)
#pragma unroll
      for (int b = 0; b < 4; ++b) acc[a][b] = (f32x4){0.f, 0.f, 0.f, 0.f};

#pragma unroll
    for (int kt = 0; kt < 16; ++kt) {
      asm volatile("s_waitcnt vmcnt(0) lgkmcnt(0)" ::: "memory");
      __builtin_amdgcn_s_barrier();   // B(kt) + A(kt+1) loads retired;
                                      // A(kt) writes visible

      if (kt <= 14) cvt_write8(awr + (kt + 1) * 8192, hA, hB);  // A(kt+1)

      const int slot = kt & 1;
      s16x8 b[4], a[4];
#pragma unroll
      for (int fn = 0; fn < 4; ++fn) b[fn] = rdB(slot, fn);
#pragma unroll
      for (int fm = 0; fm < 4; ++fm) a[fm] = rdA(kt, fm);

      if (kt < 15)
        stage_B(Bb0, lds + B_BASE + ((kt + 1) & 1) * 16384, (kt + 1) * 64,
                wave, lane);

      if (kt <= 13) {                                 // load A(kt+2)
        hA = *(const float4*)(abase + (kt + 2) * 32);
        hB = *(const float4*)(abase + (kt + 2) * 32 + 4);
      }

      __builtin_amdgcn_s_setprio(1);
#pragma unroll
      for (int fm = 0; fm < 4; ++fm)
#pragma unroll
        for (int fn = 0; fn < 4; ++fn)
          acc[fm][fn] = __builtin_amdgcn_mfma_f32_16x16x32_bf16(
              a[fm], b[fn], acc[fm][fn], 0, 0, 0);
      __builtin_amdgcn_s_setprio(0);
    }

    const int n0 = ntl0 * 256;
    const int mbase = m0 + wm * 64 + ((lane >> 4) << 2);
    const int nbase = n0 + wn * 64 + lr;
#pragma unroll
    for (int fm = 0; fm < 4; ++fm)
#pragma unroll
      for (int fn = 0; fn < 4; ++fn)
#pragma unroll
        for (int r = 0; r < 4; ++r)
          G[(size_t)(mbase + fm * 16 + r) * 3072 + nbase + fn * 16] =
              __float2bfloat16(acc[fm][fn][r]);
  }

  // ---- panels 1..5: barrier-free, B direct from L2 to registers ----
  // lane's B address for (ntl, fn, kt): W[(ntl*256 + wn*64 + fn*16 + lr)]
  // [kt*32 + (lane>>4)*8 ..], i.e. base + fn*16384 + kt*64.
  // Coalescing: lanes {lr, lr+16, lr+32, lr+48} read cols 0..63 of one row
  // -> 16 full 64B cache lines per instruction. W panel is L2-resident.
  const char* bglane = (const char*)Wb + (size_t)(wn * 64 + lr) * 1024 +
                       (lane >> 4) * 16;

  for (int i = 1; i < 6; ++i) {
    const int ntl = (i < 4) ? (type ? i + 4 : i) : (type ? i + 6 : i + 4);
    const char* bgl = bglane + (size_t)ntl * 262144;

    f32x4 acc[4][4];
#pragma unroll
    for (int a = 0; a < 4; ++a)
#pragma unroll
      for (int b = 0; b < 4; ++b) acc[a][b] = (f32x4){0.f, 0.f, 0.f, 0.f};

    s16x8 aC[4], bC[4];
#pragma unroll
    for (int fm = 0; fm < 4; ++fm) aC[fm] = rdA(0, fm);
#pragma unroll
    for (int fn = 0; fn < 4; ++fn)
      bC[fn] = *(const s16x8*)(bgl + fn * 16384);

#pragma unroll
    for (int kt = 0; kt < 16; ++kt) {
      s16x8 aN[4], bN[4];

      __builtin_amdgcn_s_setprio(1);
#pragma unroll
      for (int fm = 0; fm < 2; ++fm)
#pragma unroll
        for (int fn = 0; fn < 4; ++fn)
          acc[fm][fn] = __builtin_amdgcn_mfma_f32_16x16x32_bf16(
              aC[fm], bC[fn], acc[fm][fn], 0, 0, 0);

      if (kt < 15) {   // prefetch next ktile under the MFMA shadow
#pragma unroll
        for (int fn = 0; fn < 4; ++fn)
          bN[fn] = *(const s16x8*)(bgl + fn * 16384 + (kt + 1) * 64);
#pragma unroll
        for (int fm = 0; fm < 4; ++fm) aN[fm] = rdA(kt + 1, fm);
      }

#pragma unroll
      for (int fm = 2; fm < 4; ++fm)
#pragma unroll
        for (int fn = 0; fn < 4; ++fn)
          acc[fm][fn] = __builtin_amdgcn_mfma_f32_16x16x32_bf16(
              aC[fm], bC[fn], acc[fm][fn], 0, 0, 0);
      __builtin_amdgcn_s_setprio(0);

      if (kt < 15) {
#pragma unroll
        for (int q = 0; q < 4; ++q) { aC[q] = aN[q]; bC[q] = bN[q]; }
      }
    }

    const int n0 = ntl * 256;
    const int mbase = m0 + wm * 64 + ((lane >> 4) << 2);
    const int nbase = n0 + wn * 64 + lr;
#pragma unroll
    for (int fm = 0; fm < 4; ++fm)
#pragma unroll
      for (int fn = 0; fn < 4; ++fn)
#pragma unroll
        for (int r = 0; r < 4; ++r)
          G[(size_t)(mbase + fm * 16 + r) * 3072 + nbase + fn * 16] =
              __float2bfloat16(acc[fm][fn][r]);
  }
}

// ------------------------------ LN + gates (wave-per-row, r19) -------------
__global__ __launch_bounds__(256) void ln_gate_kernel(
    const __hip_bfloat16* __restrict__ G, const float* __restrict__ h,
    const float* __restrict__ b0, const float* __restrict__ b1,
    const float* __restrict__ b2, const float* __restrict__ b3,
    float* __restrict__ out)
{
  const int w = threadIdx.x >> 6;
  const int L = threadIdx.x & 63;
  const int row = blockIdx.x * 4 + w;
  const unsigned short* g = (const unsigned short*)(G + (size_t)row * 3072);

  __shared__ float zr[4][1024];   // transposed: col c at (c&15)*64 + (c>>4)
  float* const zw = zr[w];

  float v0[16], v1[16];
  {
    const u16x8 a0 = *(const u16x8*)(g + 16 * L);
    const u16x8 a1 = *(const u16x8*)(g + 16 * L + 8);
    const u16x8 c0 = *(const u16x8*)(g + 1024 + 16 * L);
    const u16x8 c1 = *(const u16x8*)(g + 1024 + 16 * L + 8);
#pragma unroll
    for (int q = 0; q < 4; ++q) {
      const float4 f0 = *(const float4*)(b0 + 16 * L + 4 * q);
      const float4 f1 = *(const float4*)(b1 + 16 * L + 4 * q);
      const float bb0[4] = {f0.x, f0.y, f0.z, f0.w};
      const float bb1[4] = {f1.x, f1.y, f1.z, f1.w};
#pragma unroll
      for (int j = 0; j < 4; ++j) {
        const int k = 4 * q + j;
        const unsigned short ua = (k < 8) ? a0[k] : a1[k - 8];
        const unsigned short uc = (k < 8) ? c0[k] : c1[k - 8];
        v0[k] = bfraw2f(ua) + bb0[j];
        v1[k] = bfraw2f(uc) + bb1[j];
      }
    }
  }
  float4 s = make_float4(0.f, 0.f, 0.f, 0.f);
#pragma unroll
  for (int k = 0; k < 16; ++k) {
    s.x += v0[k]; s.y += v0[k] * v0[k];
    s.z += v1[k]; s.w += v1[k] * v1[k];
  }
#pragma unroll
  for (int off = 1; off < 64; off <<= 1) {
    s.x += __shfl_xor(s.x, off);
    s.y += __shfl_xor(s.y, off);
    s.z += __shfl_xor(s.z, off);
    s.w += __shfl_xor(s.w, off);
  }
  const float mu0 = s.x * (1.f / 1024.f);
  const float mu1 = s.z * (1.f / 1024.f);
  const float rs0 = rsqrtf(s.y * (1.f / 1024.f) - mu0 * mu0 + 1e-5f);
  const float rs1 = rsqrtf(s.w * (1.f / 1024.f) - mu1 * mu1 + 1e-5f);

#pragma unroll
  for (int k = 0; k < 16; ++k) {
    const float pre = (v0[k] - mu0) * rs0 + (v1[k] - mu1) * rs1;
    zw[k * 64 + L] = 1.f / (1.f + __expf(-pre));   // c = 16L+k transposed
  }

  float v2[8], v3[8];
  {
    const u16x8 a = *(const u16x8*)(g + 2048 + 8 * L);
    const u16x8 c = *(const u16x8*)(g + 2560 + 8 * L);
#pragma unroll
    for (int q = 0; q < 2; ++q) {
      const float4 f2 = *(const float4*)(b2 + 8 * L + 4 * q);
      const float4 f3 = *(const float4*)(b3 + 8 * L + 4 * q);
      const float bb2[4] = {f2.x, f2.y, f2.z, f2.w};
      const float bb3[4] = {f3.x, f3.y, f3.z, f3.w};
#pragma unroll
      for (int j = 0; j < 4; ++j) {
        const int k = 4 * q + j;
        v2[k] = bfraw2f(a[k]) + bb2[j];
        v3[k] = bfraw2f(c[k]) + bb3[j];
      }
    }
  }
  float4 t = make_float4(0.f, 0.f, 0.f, 0.f);
#pragma unroll
  for (int k = 0; k < 8; ++k) {
    t.x += v2[k]; t.y += v2[k] * v2[k];
    t.z += v3[k]; t.w += v3[k] * v3[k];
  }
#pragma unroll
  for (int off = 1; off < 64; off <<= 1) {
    t.x += __shfl_xor(t.x, off);
    t.y += __shfl_xor(t.y, off);
    t.z += __shfl_xor(t.z, off);
    t.w += __shfl_xor(t.w, off);
  }
  const float mu2 = t.x * (1.f / 512.f);
  const float mu3 = t.z * (1.f / 512.f);
  const float rs2 = rsqrtf(t.y * (1.f / 512.f) - mu2 * mu2 + 1e-5f);
  const float rs3 = rsqrtf(t.w * (1.f / 512.f) - mu3 * mu3 + 1e-5f);

  asm volatile("s_waitcnt lgkmcnt(0)" ::: "memory");  // zw writes done

  const float4 h0 = *(const float4*)(h + (size_t)row * 512 + 8 * L);
  const float4 h1 = *(const float4*)(h + (size_t)row * 512 + 8 * L + 4);
  const float hv[8] = {h0.x, h0.y, h0.z, h0.w, h1.x, h1.y, h1.z, h1.w};

  float o[8];
#pragma unroll
  for (int k = 0; k < 8; ++k) {
    const int c  = 8 * L + k;                         // hat col
    const float z  = zw[(c & 15) * 64 + (c >> 4)];
    const float rr = zw[((512 + c) & 15) * 64 + ((512 + c) >> 4)];
    const float ha  = (v2[k] - mu2) * rs2;
    const float hbv = (v3[k] - mu3) * rs3;
    const float hhat = tanhf(ha + rr * hbv);
    o[k] = (1.f - z) * hv[k] + z * hhat;
  }
  *(float4*)(out + (size_t)row * 512 + 8 * L)     = make_float4(o[0], o[1], o[2], o[3]);
  *(float4*)(out + (size_t)row * 512 + 8 * L + 4) = make_float4(o[4], o[5], o[6], o[7]);
}

// ------------------------------- launcher ----------------------------------
extern "C" void kernel_launch(void* const* d_in, const int* in_sizes, int n_in,
                              void* d_out, int out_size, void* d_ws, size_t ws_size,
                              hipStream_t stream) {
  (void)in_sizes; (void)n_in; (void)out_size; (void)ws_size;
  const float* x      = (const float*)d_in[0];
  const float* h      = (const float*)d_in[1];
  const float* W_i2h  = (const float*)d_in[2];
  const float* b_i2h  = (const float*)d_in[3];
  const float* W_h2h  = (const float*)d_in[4];
  const float* b_h2h  = (const float*)d_in[5];
  const float* W_hatW = (const float*)d_in[6];
  const float* b_hatW = (const float*)d_in[7];
  const float* W_hatU = (const float*)d_in[8];
  const float* b_hatU = (const float*)d_in[9];
  float* out = (float*)d_out;
  __hip_bfloat16* ws = (__hip_bfloat16*)d_ws;

  convert_w_kernel<<<1536, 256, 0, stream>>>(W_i2h, W_h2h, W_hatW, W_hatU,
                                             ws + WB_OFF);
  gemm_kernel<<<256, 512, 0, stream>>>(x, h, ws + WB_OFF, ws + GB_OFF);
  ln_gate_kernel<<<4096, 256, 0, stream>>>(ws + GB_OFF, h, b_i2h, b_h2h,
                                           b_hatW, b_hatU, out);
}

// Round 21
// 97.937 us; speedup vs baseline: 1.3756x; 1.3756x over previous
//
#include <hip/hip_runtime.h>
#include <hip/hip_bf16.h>

// ---------------------------------------------------------------------------
// LayerNormGRUCell: B=16384, I=H=512
//   G = [x@W_i2h.T | h@W_h2h.T | x@W_hatW.T | h@W_hatU.T]  (16384 x 3072)
//   then per-row: LN segments + gates + tanh + lerp -> h_t (16384 x 512 fp32)
// ws layout (bf16 elements):
//   Wcat @ 0        (3072*512)    rows: [W_i2h;W_h2h;W_hatW;W_hatU]
//   Gb   @ 1572864  (16384*3072)
// Round-21: BARRIER-FREE panels via WAVE-PRIVATE B staging. Wave grid 1x8
// (per-wave 128x32, acc[8][2]): each wave's 32 B rows are read only by
// itself -> it stages them with global_load_lds into a private 2-slot ring
// (2KB/slot; 8x4KB=32KB; + A-resident 128KB = 160KB exact). Panels 1-5:
// no s_barrier at all; counted vmcnt(2) (2-ktile cover); lgkmcnt(0) before
// re-staging a slot (WAR). Panel 0 keeps the barriered A-streaming schedule
// (A writes are cross-wave), re-indexed for 1x8. One barrier at the
// panel0->1 transition (B region relayout). r20's B-from-L2 reverted.
// ---------------------------------------------------------------------------

using f32x4 = __attribute__((ext_vector_type(4))) float;
using s16x8 = __attribute__((ext_vector_type(8))) short;
typedef __attribute__((ext_vector_type(8))) unsigned short u16x8;

#define WB_OFF   0ull
#define GB_OFF   1572864ull

__device__ __forceinline__ void async_load16(const void* g, void* l) {
  __builtin_amdgcn_global_load_lds(
      (const __attribute__((address_space(1))) unsigned int*)g,
      (__attribute__((address_space(3))) unsigned int*)l, 16, 0, 0);
}

__device__ __forceinline__ float bfraw2f(unsigned short u) {
  union { unsigned int i; float f; } c;
  c.i = ((unsigned int)u) << 16;
  return c.f;
}

// -------------------------- fp32 -> bf16 weights only ----------------------
__global__ __launch_bounds__(256) void convert_w_kernel(
    const float* __restrict__ w0, const float* __restrict__ w1,
    const float* __restrict__ w2, const float* __restrict__ w3,
    __hip_bfloat16* __restrict__ dst)
{
  const size_t i = (size_t)blockIdx.x * 256 + threadIdx.x;  // vec4 index
  const float* src;
  __hip_bfloat16* d;
  size_t o;
  if (i < 131072ull)      { src = w0; d = dst;            o = i; }
  else if (i < 262144ull) { src = w1; d = dst + 524288;   o = i - 131072ull; }
  else if (i < 327680ull) { src = w2; d = dst + 1048576;  o = i - 262144ull; }
  else                    { src = w3; d = dst + 1310720;  o = i - 327680ull; }
  const float4 v = *(const float4*)(src + 4 * o);
  __hip_bfloat16 t4[4] = {__float2bfloat16(v.x), __float2bfloat16(v.y),
                          __float2bfloat16(v.z), __float2bfloat16(v.w)};
  *(uint2*)(d + 4 * o) = *(const uint2*)t4;
}

// -------------------------------- GEMM -------------------------------------
// 256 blocks x 512 threads, 1 block/CU. type=bid&1 (0=X,1=H), mband=bid>>1.
// X n-tiles {0,1,2,3,8,9}; H {4,5,6,7,10,11}. W panels L2-resident per XCD.
// LDS: A resident [kt=16][128 rows][64 B] @0 (131072 B); B region @131072:
//   panel 0: block-shared ring-2 [slot=2][256 rows][64 B] (16KB slots)
//   panels 1-5: per-wave private ring-2: wave w @ +w*4096, slots of 2KB
//   ([32 rows][64 B], rows = wave's 32 G-cols of the panel).
// Swizzle (both layouts, both sides): swz(row)=((row>>1)&3)<<4 on 16B chunks
// (for all row bases used here swz reduces to the lane-local ((lr>>1)&3)<<4
// / ((lane>>3)&3)<<4 forms -- identical algebra to the proven r7 pattern).

#define B_BASE 131072

__device__ __forceinline__ void stage_B_shared(const char* base, char* slot,
                                               int koff, int wave, int lane) {
#pragma unroll
  for (int i = 0; i < 2; ++i) {
    const int c = wave * 2 + i;
    const int row  = c * 16 + (lane >> 2);
    const int colb = ((lane & 3) * 16) ^ (((lane >> 3) & 3) << 4);  // pre-swz
    async_load16(base + (size_t)row * 1024 + koff + colb,
                 slot + c * 1024 + lane * 16);
  }
}

__device__ __forceinline__ void cvt_write8(void* dst, const float4& f0,
                                           const float4& f1) {
  union { s16x8 v; __hip_bfloat16 b[8]; } u;
  u.b[0] = __float2bfloat16(f0.x); u.b[1] = __float2bfloat16(f0.y);
  u.b[2] = __float2bfloat16(f0.z); u.b[3] = __float2bfloat16(f0.w);
  u.b[4] = __float2bfloat16(f1.x); u.b[5] = __float2bfloat16(f1.y);
  u.b[6] = __float2bfloat16(f1.z); u.b[7] = __float2bfloat16(f1.w);
  *(s16x8*)dst = u.v;
}

__global__ __launch_bounds__(512, 2) void gemm_kernel(
    const float* __restrict__ xf,
    const float* __restrict__ hf,
    const __hip_bfloat16* __restrict__ Wb,
    __hip_bfloat16* __restrict__ G)
{
  const int bid   = blockIdx.x;     // 256
  const int type  = bid & 1;        // 0 = X, 1 = H
  const int mband = bid >> 1;       // 0..127
  const int m0    = mband * 128;
  const float* Af = (type ? hf : xf) + (size_t)m0 * 512;

  __shared__ __align__(16) char lds[163840];

  const int tid  = threadIdx.x;
  const int lane = tid & 63;
  const int wave = tid >> 6;        // 1x8 wave grid: wave = wn, wm = 0

  const int lk  = (lane >> 4) * 16;
  const int lr  = lane & 15;
  const int rdk = lk ^ (((lr >> 1) & 3) << 4);     // read swizzle (A and B)

  auto rdA = [&](int kt, int fm) {  // fm 0..7, A rows fm*16+lr (wm==0)
    return *(const s16x8*)(lds + kt * 8192 + (fm * 16 + lr) * 64 + rdk);
  };
  auto rdB0 = [&](int slot, int fn) {  // panel-0 block-shared layout
    return *(const s16x8*)(lds + B_BASE + slot * 16384 +
                           (wave * 32 + fn * 16 + lr) * 64 + rdk);
  };

  const int ntl0 = type ? 4 : 0;
  const char* Bb0 = (const char*)Wb + (size_t)ntl0 * 256 * 1024;

  stage_B_shared(Bb0, lds + B_BASE, 0, wave, lane);

  // ---- A streaming setup: LINEAR source, SWIZZLED LDS dest (rule 21) ----
  const int arow = tid >> 2;                         // 0..127
  const int alin = (tid & 3) * 16;                   // linear byte pos
  const int acb  = alin ^ (((arow >> 1) & 3) << 4);  // swizzled LDS pos
  const float* abase = Af + (size_t)arow * 512 + (alin >> 1);
  char* const awr = lds + arow * 64 + acb;           // + kt*8192

  float4 hA, hB;
  {
    const float4 a0 = *(const float4*)(abase);       // A(0)
    const float4 a1 = *(const float4*)(abase + 4);
    hA = *(const float4*)(abase + 32);               // A(1)
    hB = *(const float4*)(abase + 36);
    cvt_write8(awr, a0, a1);                         // write A(0)
  }

  // ---- panel 0: compute ntl0 while streaming A into residence ----
  {
    f32x4 acc[8][2];
#pragma unroll
    for (int a = 0; a < 8; ++a)
#pragma unroll
      for (int b = 0; b < 2; ++b) acc[a][b] = (f32x4){0.f, 0.f, 0.f, 0.f};

#pragma unroll
    for (int kt = 0; kt < 16; ++kt) {
      asm volatile("s_waitcnt vmcnt(0) lgkmcnt(0)" ::: "memory");
      __builtin_amdgcn_s_barrier();   // B(kt)+A(kt+1) retired; A(kt) visible

      if (kt <= 14) cvt_write8(awr + (kt + 1) * 8192, hA, hB);  // A(kt+1)

      const int slot = kt & 1;
      s16x8 b[2], a[8];
#pragma unroll
      for (int fn = 0; fn < 2; ++fn) b[fn] = rdB0(slot, fn);
#pragma unroll
      for (int fm = 0; fm < 8; ++fm) a[fm] = rdA(kt, fm);

      if (kt < 15)
        stage_B_shared(Bb0, lds + B_BASE + ((kt + 1) & 1) * 16384,
                       (kt + 1) * 64, wave, lane);

      if (kt <= 13) {                                 // load A(kt+2)
        hA = *(const float4*)(abase + (kt + 2) * 32);
        hB = *(const float4*)(abase + (kt + 2) * 32 + 4);
      }

      __builtin_amdgcn_s_setprio(1);
#pragma unroll
      for (int fm = 0; fm < 8; ++fm)
#pragma unroll
        for (int fn = 0; fn < 2; ++fn)
          acc[fm][fn] = __builtin_amdgcn_mfma_f32_16x16x32_bf16(
              a[fm], b[fn], acc[fm][fn], 0, 0, 0);
      __builtin_amdgcn_s_setprio(0);
    }

    const int n0 = ntl0 * 256;
    const int mbase = m0 + ((lane >> 4) << 2);
    const int nbase = n0 + wave * 32 + lr;
#pragma unroll
    for (int fm = 0; fm < 8; ++fm)
#pragma unroll
      for (int fn = 0; fn < 2; ++fn)
#pragma unroll
        for (int r = 0; r < 4; ++r)
          G[(size_t)(mbase + fm * 16 + r) * 3072 + nbase + fn * 16] =
              __float2bfloat16(acc[fm][fn][r]);
  }

  // transition: protect B region relayout (shared ring -> private rings)
  __builtin_amdgcn_s_barrier();

  // ---- panels 1..5: barrier-free, per-wave-private B staging ----
  char* const pB = lds + B_BASE + wave * 4096;   // 2 slots x 2048 B
  const char* const wpriv0 = (const char*)Wb + (size_t)wave * 32768;

  auto rdBp = [&](int slot, int fn) {
    return *(const s16x8*)(pB + slot * 2048 + (fn * 16 + lr) * 64 + rdk);
  };
  auto stage_Bp = [&](int ntl, int kt, int slot) {
    const char* wb = wpriv0 + (size_t)ntl * 262144;
#pragma unroll
    for (int ii = 0; ii < 2; ++ii) {
      const int row  = ii * 16 + (lane >> 2);
      const int colb = ((lane & 3) * 16) ^ (((lane >> 3) & 3) << 4);
      async_load16(wb + (size_t)row * 1024 + kt * 64 + colb,
                   pB + slot * 2048 + ii * 1024 + lane * 16);
    }
  };

  {
    const int ntl1 = type ? 5 : 1;
    stage_Bp(ntl1, 0, 0);
    stage_Bp(ntl1, 1, 1);
  }

  for (int ip = 1; ip < 6; ++ip) {
    const int ntl  = (ip < 4) ? (type ? ip + 4 : ip) : (type ? ip + 6 : ip + 4);
    const int ipn  = ip + 1;
    const int ntlN = (ip < 5) ? ((ipn < 4) ? (type ? ipn + 4 : ipn)
                                           : (type ? ipn + 6 : ipn + 4)) : ntl;

    f32x4 acc[8][2];
#pragma unroll
    for (int a = 0; a < 8; ++a)
#pragma unroll
      for (int b = 0; b < 2; ++b) acc[a][b] = (f32x4){0.f, 0.f, 0.f, 0.f};

#pragma unroll
    for (int kt = 0; kt < 16; ++kt) {
      // counted per-wave wait: B(kt) resident, B(kt+1) stays in flight
      if (ip == 5 && kt == 15) asm volatile("s_waitcnt vmcnt(0)" ::: "memory");
      else                     asm volatile("s_waitcnt vmcnt(2)" ::: "memory");

      const int slot = kt & 1;
      s16x8 b[2], a[8];
#pragma unroll
      for (int fn = 0; fn < 2; ++fn) b[fn] = rdBp(slot, fn);
#pragma unroll
      for (int fm = 0; fm < 8; ++fm) a[fm] = rdA(kt, fm);

      // drain ds_reads before overwriting this slot (WAR), then re-stage
      asm volatile("s_waitcnt lgkmcnt(0)" ::: "memory");
      __builtin_amdgcn_sched_barrier(0);   // rule 18
      if (kt <= 13)    stage_Bp(ntl, kt + 2, slot);
      else if (ip < 5) stage_Bp(ntlN, kt - 14, slot);  // parity matches

      __builtin_amdgcn_s_setprio(1);
#pragma unroll
      for (int fm = 0; fm < 8; ++fm)
#pragma unroll
        for (int fn = 0; fn < 2; ++fn)
          acc[fm][fn] = __builtin_amdgcn_mfma_f32_16x16x32_bf16(
              a[fm], b[fn], acc[fm][fn], 0, 0, 0);
      __builtin_amdgcn_s_setprio(0);
    }

    const int n0 = ntl * 256;
    const int mbase = m0 + ((lane >> 4) << 2);
    const int nbase = n0 + wave * 32 + lr;
#pragma unroll
    for (int fm = 0; fm < 8; ++fm)
#pragma unroll
      for (int fn = 0; fn < 2; ++fn)
#pragma unroll
        for (int r = 0; r < 4; ++r)
          G[(size_t)(mbase + fm * 16 + r) * 3072 + nbase + fn * 16] =
              __float2bfloat16(acc[fm][fn][r]);
  }
}

// ------------------------------ LN + gates (wave-per-row, r19) -------------
__global__ __launch_bounds__(256) void ln_gate_kernel(
    const __hip_bfloat16* __restrict__ G, const float* __restrict__ h,
    const float* __restrict__ b0, const float* __restrict__ b1,
    const float* __restrict__ b2, const float* __restrict__ b3,
    float* __restrict__ out)
{
  const int w = threadIdx.x >> 6;
  const int L = threadIdx.x & 63;
  const int row = blockIdx.x * 4 + w;
  const unsigned short* g = (const unsigned short*)(G + (size_t)row * 3072);

  __shared__ float zr[4][1024];   // transposed: col c at (c&15)*64 + (c>>4)
  float* const zw = zr[w];

  float v0[16], v1[16];
  {
    const u16x8 a0 = *(const u16x8*)(g + 16 * L);
    const u16x8 a1 = *(const u16x8*)(g + 16 * L + 8);
    const u16x8 c0 = *(const u16x8*)(g + 1024 + 16 * L);
    const u16x8 c1 = *(const u16x8*)(g + 1024 + 16 * L + 8);
#pragma unroll
    for (int q = 0; q < 4; ++q) {
      const float4 f0 = *(const float4*)(b0 + 16 * L + 4 * q);
      const float4 f1 = *(const float4*)(b1 + 16 * L + 4 * q);
      const float bb0[4] = {f0.x, f0.y, f0.z, f0.w};
      const float bb1[4] = {f1.x, f1.y, f1.z, f1.w};
#pragma unroll
      for (int j = 0; j < 4; ++j) {
        const int k = 4 * q + j;
        const unsigned short ua = (k < 8) ? a0[k] : a1[k - 8];
        const unsigned short uc = (k < 8) ? c0[k] : c1[k - 8];
        v0[k] = bfraw2f(ua) + bb0[j];
        v1[k] = bfraw2f(uc) + bb1[j];
      }
    }
  }
  float4 s = make_float4(0.f, 0.f, 0.f, 0.f);
#pragma unroll
  for (int k = 0; k < 16; ++k) {
    s.x += v0[k]; s.y += v0[k] * v0[k];
    s.z += v1[k]; s.w += v1[k] * v1[k];
  }
#pragma unroll
  for (int off = 1; off < 64; off <<= 1) {
    s.x += __shfl_xor(s.x, off);
    s.y += __shfl_xor(s.y, off);
    s.z += __shfl_xor(s.z, off);
    s.w += __shfl_xor(s.w, off);
  }
  const float mu0 = s.x * (1.f / 1024.f);
  const float mu1 = s.z * (1.f / 1024.f);
  const float rs0 = rsqrtf(s.y * (1.f / 1024.f) - mu0 * mu0 + 1e-5f);
  const float rs1 = rsqrtf(s.w * (1.f / 1024.f) - mu1 * mu1 + 1e-5f);

#pragma unroll
  for (int k = 0; k < 16; ++k) {
    const float pre = (v0[k] - mu0) * rs0 + (v1[k] - mu1) * rs1;
    zw[k * 64 + L] = 1.f / (1.f + __expf(-pre));   // c = 16L+k transposed
  }

  float v2[8], v3[8];
  {
    const u16x8 a = *(const u16x8*)(g + 2048 + 8 * L);
    const u16x8 c = *(const u16x8*)(g + 2560 + 8 * L);
#pragma unroll
    for (int q = 0; q < 2; ++q) {
      const float4 f2 = *(const float4*)(b2 + 8 * L + 4 * q);
      const float4 f3 = *(const float4*)(b3 + 8 * L + 4 * q);
      const float bb2[4] = {f2.x, f2.y, f2.z, f2.w};
      const float bb3[4] = {f3.x, f3.y, f3.z, f3.w};
#pragma unroll
      for (int j = 0; j < 4; ++j) {
        const int k = 4 * q + j;
        v2[k] = bfraw2f(a[k]) + bb2[j];
        v3[k] = bfraw2f(c[k]) + bb3[j];
      }
    }
  }
  float4 t = make_float4(0.f, 0.f, 0.f, 0.f);
#pragma unroll
  for (int k = 0; k < 8; ++k) {
    t.x += v2[k]; t.y += v2[k] * v2[k];
    t.z += v3[k]; t.w += v3[k] * v3[k];
  }
#pragma unroll
  for (int off = 1; off < 64; off <<= 1) {
    t.x += __shfl_xor(t.x, off);
    t.y += __shfl_xor(t.y, off);
    t.z += __shfl_xor(t.z, off);
    t.w += __shfl_xor(t.w, off);
  }
  const float mu2 = t.x * (1.f / 512.f);
  const float mu3 = t.z * (1.f / 512.f);
  const float rs2 = rsqrtf(t.y * (1.f / 512.f) - mu2 * mu2 + 1e-5f);
  const float rs3 = rsqrtf(t.w * (1.f / 512.f) - mu3 * mu3 + 1e-5f);

  asm volatile("s_waitcnt lgkmcnt(0)" ::: "memory");  // zw writes done

  const float4 h0 = *(const float4*)(h + (size_t)row * 512 + 8 * L);
  const float4 h1 = *(const float4*)(h + (size_t)row * 512 + 8 * L + 4);
  const float hv[8] = {h0.x, h0.y, h0.z, h0.w, h1.x, h1.y, h1.z, h1.w};

  float o[8];
#pragma unroll
  for (int k = 0; k < 8; ++k) {
    const int c  = 8 * L + k;                         // hat col
    const float z  = zw[(c & 15) * 64 + (c >> 4)];
    const float rr = zw[((512 + c) & 15) * 64 + ((512 + c) >> 4)];
    const float ha  = (v2[k] - mu2) * rs2;
    const float hbv = (v3[k] - mu3) * rs3;
    const float hhat = tanhf(ha + rr * hbv);
    o[k] = (1.f - z) * hv[k] + z * hhat;
  }
  *(float4*)(out + (size_t)row * 512 + 8 * L)     = make_float4(o[0], o[1], o[2], o[3]);
  *(float4*)(out + (size_t)row * 512 + 8 * L + 4) = make_float4(o[4], o[5], o[6], o[7]);
}

// ------------------------------- launcher ----------------------------------
extern "C" void kernel_launch(void* const* d_in, const int* in_sizes, int n_in,
                              void* d_out, int out_size, void* d_ws, size_t ws_size,
                              hipStream_t stream) {
  (void)in_sizes; (void)n_in; (void)out_size; (void)ws_size;
  const float* x      = (const float*)d_in[0];
  const float* h      = (const float*)d_in[1];
  const float* W_i2h  = (const float*)d_in[2];
  const float* b_i2h  = (const float*)d_in[3];
  const float* W_h2h  = (const float*)d_in[4];
  const float* b_h2h  = (const float*)d_in[5];
  const float* W_hatW = (const float*)d_in[6];
  const float* b_hatW = (const float*)d_in[7];
  const float* W_hatU = (const float*)d_in[8];
  const float* b_hatU = (const float*)d_in[9];
  float* out = (float*)d_out;
  __hip_bfloat16* ws = (__hip_bfloat16*)d_ws;

  convert_w_kernel<<<1536, 256, 0, stream>>>(W_i2h, W_h2h, W_hatW, W_hatU,
                                             ws + WB_OFF);
  gemm_kernel<<<256, 512, 0, stream>>>(x, h, ws + WB_OFF, ws + GB_OFF);
  ln_gate_kernel<<<4096, 256, 0, stream>>>(ws + GB_OFF, h, b_i2h, b_h2h,
                                           b_hatW, b_hatU, out);
}

// Round 22
// 97.700 us; speedup vs baseline: 1.3789x; 1.0024x over previous
//
#include <hip/hip_runtime.h>
#include <hip/hip_bf16.h>

// ---------------------------------------------------------------------------
// LayerNormGRUCell: B=16384, I=H=512
//   G = [x@W_i2h.T | h@W_h2h.T | x@W_hatW.T | h@W_hatU.T]  (16384 x 3072)
//   then per-row: LN segments + gates + tanh + lerp -> h_t (16384 x 512 fp32)
// ws layout (bf16 elements):
//   Wcat @ 0        (3072*512)    rows: [W_i2h;W_h2h;W_hatW;W_hatU]
//   Gb   @ 1572864  (16384*3072)
// Round-22: r21 + A-FRAGMENT REGISTER DOUBLE-BUFFER in panels 1-5.
// A is immutable and identical across panels -> prefetch rdA((kt+1)&15)
// inside the MFMA cluster (wraps to next panel's kt0 at kt=15; aC carries
// across panel boundaries). Per-ktile lgkmcnt(0) now drains only the 2
// fresh B reads instead of all 10 -- the 8 A reads retire under the
// previous ktile's MFMA shadow. Everything else = r21 verbatim.
// ---------------------------------------------------------------------------

using f32x4 = __attribute__((ext_vector_type(4))) float;
using s16x8 = __attribute__((ext_vector_type(8))) short;
typedef __attribute__((ext_vector_type(8))) unsigned short u16x8;

#define WB_OFF   0ull
#define GB_OFF   1572864ull

__device__ __forceinline__ void async_load16(const void* g, void* l) {
  __builtin_amdgcn_global_load_lds(
      (const __attribute__((address_space(1))) unsigned int*)g,
      (__attribute__((address_space(3))) unsigned int*)l, 16, 0, 0);
}

__device__ __forceinline__ float bfraw2f(unsigned short u) {
  union { unsigned int i; float f; } c;
  c.i = ((unsigned int)u) << 16;
  return c.f;
}

// -------------------------- fp32 -> bf16 weights only ----------------------
__global__ __launch_bounds__(256) void convert_w_kernel(
    const float* __restrict__ w0, const float* __restrict__ w1,
    const float* __restrict__ w2, const float* __restrict__ w3,
    __hip_bfloat16* __restrict__ dst)
{
  const size_t i = (size_t)blockIdx.x * 256 + threadIdx.x;  // vec4 index
  const float* src;
  __hip_bfloat16* d;
  size_t o;
  if (i < 131072ull)      { src = w0; d = dst;            o = i; }
  else if (i < 262144ull) { src = w1; d = dst + 524288;   o = i - 131072ull; }
  else if (i < 327680ull) { src = w2; d = dst + 1048576;  o = i - 262144ull; }
  else                    { src = w3; d = dst + 1310720;  o = i - 327680ull; }
  const float4 v = *(const float4*)(src + 4 * o);
  __hip_bfloat16 t4[4] = {__float2bfloat16(v.x), __float2bfloat16(v.y),
                          __float2bfloat16(v.z), __float2bfloat16(v.w)};
  *(uint2*)(d + 4 * o) = *(const uint2*)t4;
}

// -------------------------------- GEMM -------------------------------------
// 256 blocks x 512 threads, 1 block/CU. type=bid&1 (0=X,1=H), mband=bid>>1.
// X n-tiles {0,1,2,3,8,9}; H {4,5,6,7,10,11}. W panels L2-resident per XCD.
// LDS: A resident [kt=16][128 rows][64 B] @0 (131072 B); B region @131072:
//   panel 0: block-shared ring-2 (16KB slots); panels 1-5: per-wave private
//   ring-2 (wave w @ +w*4096, 2KB slots of [32 rows][64 B]).
// Swizzle: swz(row)=((row>>1)&3)<<4 on 16B chunks (r7-proven, 0 conflicts).

#define B_BASE 131072

__device__ __forceinline__ void stage_B_shared(const char* base, char* slot,
                                               int koff, int wave, int lane) {
#pragma unroll
  for (int i = 0; i < 2; ++i) {
    const int c = wave * 2 + i;
    const int row  = c * 16 + (lane >> 2);
    const int colb = ((lane & 3) * 16) ^ (((lane >> 3) & 3) << 4);  // pre-swz
    async_load16(base + (size_t)row * 1024 + koff + colb,
                 slot + c * 1024 + lane * 16);
  }
}

__device__ __forceinline__ void cvt_write8(void* dst, const float4& f0,
                                           const float4& f1) {
  union { s16x8 v; __hip_bfloat16 b[8]; } u;
  u.b[0] = __float2bfloat16(f0.x); u.b[1] = __float2bfloat16(f0.y);
  u.b[2] = __float2bfloat16(f0.z); u.b[3] = __float2bfloat16(f0.w);
  u.b[4] = __float2bfloat16(f1.x); u.b[5] = __float2bfloat16(f1.y);
  u.b[6] = __float2bfloat16(f1.z); u.b[7] = __float2bfloat16(f1.w);
  *(s16x8*)dst = u.v;
}

__global__ __launch_bounds__(512, 2) void gemm_kernel(
    const float* __restrict__ xf,
    const float* __restrict__ hf,
    const __hip_bfloat16* __restrict__ Wb,
    __hip_bfloat16* __restrict__ G)
{
  const int bid   = blockIdx.x;     // 256
  const int type  = bid & 1;        // 0 = X, 1 = H
  const int mband = bid >> 1;       // 0..127
  const int m0    = mband * 128;
  const float* Af = (type ? hf : xf) + (size_t)m0 * 512;

  __shared__ __align__(16) char lds[163840];

  const int tid  = threadIdx.x;
  const int lane = tid & 63;
  const int wave = tid >> 6;        // 1x8 wave grid: wave = wn, wm = 0

  const int lk  = (lane >> 4) * 16;
  const int lr  = lane & 15;
  const int rdk = lk ^ (((lr >> 1) & 3) << 4);     // read swizzle (A and B)

  auto rdA = [&](int kt, int fm) {  // fm 0..7, A rows fm*16+lr (wm==0)
    return *(const s16x8*)(lds + kt * 8192 + (fm * 16 + lr) * 64 + rdk);
  };
  auto rdB0 = [&](int slot, int fn) {  // panel-0 block-shared layout
    return *(const s16x8*)(lds + B_BASE + slot * 16384 +
                           (wave * 32 + fn * 16 + lr) * 64 + rdk);
  };

  const int ntl0 = type ? 4 : 0;
  const char* Bb0 = (const char*)Wb + (size_t)ntl0 * 256 * 1024;

  stage_B_shared(Bb0, lds + B_BASE, 0, wave, lane);

  // ---- A streaming setup: LINEAR source, SWIZZLED LDS dest (rule 21) ----
  const int arow = tid >> 2;                         // 0..127
  const int alin = (tid & 3) * 16;                   // linear byte pos
  const int acb  = alin ^ (((arow >> 1) & 3) << 4);  // swizzled LDS pos
  const float* abase = Af + (size_t)arow * 512 + (alin >> 1);
  char* const awr = lds + arow * 64 + acb;           // + kt*8192

  float4 hA, hB;
  {
    const float4 a0 = *(const float4*)(abase);       // A(0)
    const float4 a1 = *(const float4*)(abase + 4);
    hA = *(const float4*)(abase + 32);               // A(1)
    hB = *(const float4*)(abase + 36);
    cvt_write8(awr, a0, a1);                         // write A(0)
  }

  // ---- panel 0: compute ntl0 while streaming A into residence ----
  {
    f32x4 acc[8][2];
#pragma unroll
    for (int a = 0; a < 8; ++a)
#pragma unroll
      for (int b = 0; b < 2; ++b) acc[a][b] = (f32x4){0.f, 0.f, 0.f, 0.f};

#pragma unroll
    for (int kt = 0; kt < 16; ++kt) {
      asm volatile("s_waitcnt vmcnt(0) lgkmcnt(0)" ::: "memory");
      __builtin_amdgcn_s_barrier();   // B(kt)+A(kt+1) retired; A(kt) visible

      if (kt <= 14) cvt_write8(awr + (kt + 1) * 8192, hA, hB);  // A(kt+1)

      const int slot = kt & 1;
      s16x8 b[2], a[8];
#pragma unroll
      for (int fn = 0; fn < 2; ++fn) b[fn] = rdB0(slot, fn);
#pragma unroll
      for (int fm = 0; fm < 8; ++fm) a[fm] = rdA(kt, fm);

      if (kt < 15)
        stage_B_shared(Bb0, lds + B_BASE + ((kt + 1) & 1) * 16384,
                       (kt + 1) * 64, wave, lane);

      if (kt <= 13) {                                 // load A(kt+2)
        hA = *(const float4*)(abase + (kt + 2) * 32);
        hB = *(const float4*)(abase + (kt + 2) * 32 + 4);
      }

      __builtin_amdgcn_s_setprio(1);
#pragma unroll
      for (int fm = 0; fm < 8; ++fm)
#pragma unroll
        for (int fn = 0; fn < 2; ++fn)
          acc[fm][fn] = __builtin_amdgcn_mfma_f32_16x16x32_bf16(
              a[fm], b[fn], acc[fm][fn], 0, 0, 0);
      __builtin_amdgcn_s_setprio(0);
    }

    const int n0 = ntl0 * 256;
    const int mbase = m0 + ((lane >> 4) << 2);
    const int nbase = n0 + wave * 32 + lr;
#pragma unroll
    for (int fm = 0; fm < 8; ++fm)
#pragma unroll
      for (int fn = 0; fn < 2; ++fn)
#pragma unroll
        for (int r = 0; r < 4; ++r)
          G[(size_t)(mbase + fm * 16 + r) * 3072 + nbase + fn * 16] =
              __float2bfloat16(acc[fm][fn][r]);
  }

  // transition: protect B region relayout (shared ring -> private rings)
  __builtin_amdgcn_s_barrier();

  // ---- panels 1..5: barrier-free, per-wave-private B, A reg-dbuf ----
  char* const pB = lds + B_BASE + wave * 4096;   // 2 slots x 2048 B
  const char* const wpriv0 = (const char*)Wb + (size_t)wave * 32768;

  auto rdBp = [&](int slot, int fn) {
    return *(const s16x8*)(pB + slot * 2048 + (fn * 16 + lr) * 64 + rdk);
  };
  auto stage_Bp = [&](int ntl, int kt, int slot) {
    const char* wb = wpriv0 + (size_t)ntl * 262144;
#pragma unroll
    for (int ii = 0; ii < 2; ++ii) {
      const int row  = ii * 16 + (lane >> 2);
      const int colb = ((lane & 3) * 16) ^ (((lane >> 3) & 3) << 4);
      async_load16(wb + (size_t)row * 1024 + kt * 64 + colb,
                   pB + slot * 2048 + ii * 1024 + lane * 16);
    }
  };

  {
    const int ntl1 = type ? 5 : 1;
    stage_Bp(ntl1, 0, 0);
    stage_Bp(ntl1, 1, 1);
  }

  // prefetch A frags for kt=0 (A resident + immutable from here on)
  s16x8 aC[8];
#pragma unroll
  for (int fm = 0; fm < 8; ++fm) aC[fm] = rdA(0, fm);

  for (int ip = 1; ip < 6; ++ip) {
    const int ntl  = (ip < 4) ? (type ? ip + 4 : ip) : (type ? ip + 6 : ip + 4);
    const int ipn  = ip + 1;
    const int ntlN = (ip < 5) ? ((ipn < 4) ? (type ? ipn + 4 : ipn)
                                           : (type ? ipn + 6 : ipn + 4)) : ntl;

    f32x4 acc[8][2];
#pragma unroll
    for (int a = 0; a < 8; ++a)
#pragma unroll
      for (int b = 0; b < 2; ++b) acc[a][b] = (f32x4){0.f, 0.f, 0.f, 0.f};

#pragma unroll
    for (int kt = 0; kt < 16; ++kt) {
      // counted per-wave wait: B(kt) resident, B(kt+1) stays in flight
      if (ip == 5 && kt == 15) asm volatile("s_waitcnt vmcnt(0)" ::: "memory");
      else                     asm volatile("s_waitcnt vmcnt(2)" ::: "memory");

      const int slot = kt & 1;
      s16x8 b[2];
#pragma unroll
      for (int fn = 0; fn < 2; ++fn) b[fn] = rdBp(slot, fn);

      // drain fresh B reads (A prefetches already retired) before slot reuse
      asm volatile("s_waitcnt lgkmcnt(0)" ::: "memory");
      __builtin_amdgcn_sched_barrier(0);   // rule 18
      if (kt <= 13)    stage_Bp(ntl, kt + 2, slot);
      else if (ip < 5) stage_Bp(ntlN, kt - 14, slot);  // parity matches

      __builtin_amdgcn_s_setprio(1);
#pragma unroll
      for (int fm = 0; fm < 4; ++fm)
#pragma unroll
        for (int fn = 0; fn < 2; ++fn)
          acc[fm][fn] = __builtin_amdgcn_mfma_f32_16x16x32_bf16(
              aC[fm], b[fn], acc[fm][fn], 0, 0, 0);

      // prefetch next ktile's A frags under the MFMA shadow; (kt+1)&15
      // wraps to kt0 for the next panel (same A for all panels)
      s16x8 aN[8];
#pragma unroll
      for (int fm = 0; fm < 8; ++fm) aN[fm] = rdA((kt + 1) & 15, fm);

#pragma unroll
      for (int fm = 4; fm < 8; ++fm)
#pragma unroll
        for (int fn = 0; fn < 2; ++fn)
          acc[fm][fn] = __builtin_amdgcn_mfma_f32_16x16x32_bf16(
              aC[fm], b[fn], acc[fm][fn], 0, 0, 0);
      __builtin_amdgcn_s_setprio(0);

#pragma unroll
      for (int q = 0; q < 8; ++q) aC[q] = aN[q];
    }

    const int n0 = ntl * 256;
    const int mbase = m0 + ((lane >> 4) << 2);
    const int nbase = n0 + wave * 32 + lr;
#pragma unroll
    for (int fm = 0; fm < 8; ++fm)
#pragma unroll
      for (int fn = 0; fn < 2; ++fn)
#pragma unroll
        for (int r = 0; r < 4; ++r)
          G[(size_t)(mbase + fm * 16 + r) * 3072 + nbase + fn * 16] =
              __float2bfloat16(acc[fm][fn][r]);
  }
}

// ------------------------------ LN + gates (wave-per-row, r19) -------------
__global__ __launch_bounds__(256) void ln_gate_kernel(
    const __hip_bfloat16* __restrict__ G, const float* __restrict__ h,
    const float* __restrict__ b0, const float* __restrict__ b1,
    const float* __restrict__ b2, const float* __restrict__ b3,
    float* __restrict__ out)
{
  const int w = threadIdx.x >> 6;
  const int L = threadIdx.x & 63;
  const int row = blockIdx.x * 4 + w;
  const unsigned short* g = (const unsigned short*)(G + (size_t)row * 3072);

  __shared__ float zr[4][1024];   // transposed: col c at (c&15)*64 + (c>>4)
  float* const zw = zr[w];

  float v0[16], v1[16];
  {
    const u16x8 a0 = *(const u16x8*)(g + 16 * L);
    const u16x8 a1 = *(const u16x8*)(g + 16 * L + 8);
    const u16x8 c0 = *(const u16x8*)(g + 1024 + 16 * L);
    const u16x8 c1 = *(const u16x8*)(g + 1024 + 16 * L + 8);
#pragma unroll
    for (int q = 0; q < 4; ++q) {
      const float4 f0 = *(const float4*)(b0 + 16 * L + 4 * q);
      const float4 f1 = *(const float4*)(b1 + 16 * L + 4 * q);
      const float bb0[4] = {f0.x, f0.y, f0.z, f0.w};
      const float bb1[4] = {f1.x, f1.y, f1.z, f1.w};
#pragma unroll
      for (int j = 0; j < 4; ++j) {
        const int k = 4 * q + j;
        const unsigned short ua = (k < 8) ? a0[k] : a1[k - 8];
        const unsigned short uc = (k < 8) ? c0[k] : c1[k - 8];
        v0[k] = bfraw2f(ua) + bb0[j];
        v1[k] = bfraw2f(uc) + bb1[j];
      }
    }
  }
  float4 s = make_float4(0.f, 0.f, 0.f, 0.f);
#pragma unroll
  for (int k = 0; k < 16; ++k) {
    s.x += v0[k]; s.y += v0[k] * v0[k];
    s.z += v1[k]; s.w += v1[k] * v1[k];
  }
#pragma unroll
  for (int off = 1; off < 64; off <<= 1) {
    s.x += __shfl_xor(s.x, off);
    s.y += __shfl_xor(s.y, off);
    s.z += __shfl_xor(s.z, off);
    s.w += __shfl_xor(s.w, off);
  }
  const float mu0 = s.x * (1.f / 1024.f);
  const float mu1 = s.z * (1.f / 1024.f);
  const float rs0 = rsqrtf(s.y * (1.f / 1024.f) - mu0 * mu0 + 1e-5f);
  const float rs1 = rsqrtf(s.w * (1.f / 1024.f) - mu1 * mu1 + 1e-5f);

#pragma unroll
  for (int k = 0; k < 16; ++k) {
    const float pre = (v0[k] - mu0) * rs0 + (v1[k] - mu1) * rs1;
    zw[k * 64 + L] = 1.f / (1.f + __expf(-pre));   // c = 16L+k transposed
  }

  float v2[8], v3[8];
  {
    const u16x8 a = *(const u16x8*)(g + 2048 + 8 * L);
    const u16x8 c = *(const u16x8*)(g + 2560 + 8 * L);
#pragma unroll
    for (int q = 0; q < 2; ++q) {
      const float4 f2 = *(const float4*)(b2 + 8 * L + 4 * q);
      const float4 f3 = *(const float4*)(b3 + 8 * L + 4 * q);
      const float bb2[4] = {f2.x, f2.y, f2.z, f2.w};
      const float bb3[4] = {f3.x, f3.y, f3.z, f3.w};
#pragma unroll
      for (int j = 0; j < 4; ++j) {
        const int k = 4 * q + j;
        v2[k] = bfraw2f(a[k]) + bb2[j];
        v3[k] = bfraw2f(c[k]) + bb3[j];
      }
    }
  }
  float4 t = make_float4(0.f, 0.f, 0.f, 0.f);
#pragma unroll
  for (int k = 0; k < 8; ++k) {
    t.x += v2[k]; t.y += v2[k] * v2[k];
    t.z += v3[k]; t.w += v3[k] * v3[k];
  }
#pragma unroll
  for (int off = 1; off < 64; off <<= 1) {
    t.x += __shfl_xor(t.x, off);
    t.y += __shfl_xor(t.y, off);
    t.z += __shfl_xor(t.z, off);
    t.w += __shfl_xor(t.w, off);
  }
  const float mu2 = t.x * (1.f / 512.f);
  const float mu3 = t.z * (1.f / 512.f);
  const float rs2 = rsqrtf(t.y * (1.f / 512.f) - mu2 * mu2 + 1e-5f);
  const float rs3 = rsqrtf(t.w * (1.f / 512.f) - mu3 * mu3 + 1e-5f);

  asm volatile("s_waitcnt lgkmcnt(0)" ::: "memory");  // zw writes done

  const float4 h0 = *(const float4*)(h + (size_t)row * 512 + 8 * L);
  const float4 h1 = *(const float4*)(h + (size_t)row * 512 + 8 * L + 4);
  const float hv[8] = {h0.x, h0.y, h0.z, h0.w, h1.x, h1.y, h1.z, h1.w};

  float o[8];
#pragma unroll
  for (int k = 0; k < 8; ++k) {
    const int c  = 8 * L + k;                         // hat col
    const float z  = zw[(c & 15) * 64 + (c >> 4)];
    const float rr = zw[((512 + c) & 15) * 64 + ((512 + c) >> 4)];
    const float ha  = (v2[k] - mu2) * rs2;
    const float hbv = (v3[k] - mu3) * rs3;
    const float hhat = tanhf(ha + rr * hbv);
    o[k] = (1.f - z) * hv[k] + z * hhat;
  }
  *(float4*)(out + (size_t)row * 512 + 8 * L)     = make_float4(o[0], o[1], o[2], o[3]);
  *(float4*)(out + (size_t)row * 512 + 8 * L + 4) = make_float4(o[4], o[5], o[6], o[7]);
}

// ------------------------------- launcher ----------------------------------
extern "C" void kernel_launch(void* const* d_in, const int* in_sizes, int n_in,
                              void* d_out, int out_size, void* d_ws, size_t ws_size,
                              hipStream_t stream) {
  (void)in_sizes; (void)n_in; (void)out_size; (void)ws_size;
  const float* x      = (const float*)d_in[0];
  const float* h      = (const float*)d_in[1];
  const float* W_i2h  = (const float*)d_in[2];
  const float* b_i2h  = (const float*)d_in[3];
  const float* W_h2h  = (const float*)d_in[4];
  const float* b_h2h  = (const float*)d_in[5];
  const float* W_hatW = (const float*)d_in[6];
  const float* b_hatW = (const float*)d_in[7];
  const float* W_hatU = (const float*)d_in[8];
  const float* b_hatU = (const float*)d_in[9];
  float* out = (float*)d_out;
  __hip_bfloat16* ws = (__hip_bfloat16*)d_ws;

  convert_w_kernel<<<1536, 256, 0, stream>>>(W_i2h, W_h2h, W_hatW, W_hatU,
                                             ws + WB_OFF);
  gemm_kernel<<<256, 512, 0, stream>>>(x, h, ws + WB_OFF, ws + GB_OFF);
  ln_gate_kernel<<<4096, 256, 0, stream>>>(ws + GB_OFF, h, b_i2h, b_h2h,
                                           b_hatW, b_hatU, out);
}

// Round 24
// 96.886 us; speedup vs baseline: 1.3905x; 1.0084x over previous
//
#include <hip/hip_runtime.h>
#include <hip/hip_bf16.h>

// ---------------------------------------------------------------------------
// LayerNormGRUCell: B=16384, I=H=512
//   G = [x@W_i2h.T | h@W_h2h.T | x@W_hatW.T | h@W_hatU.T]  (16384 x 3072)
//   then per-row: LN segments + gates + tanh + lerp -> h_t (16384 x 512 fp32)
// ws layout (bf16 elements):
//   Wcat @ 0        (3072*512)    rows: [W_i2h;W_h2h;W_hatW;W_hatU]
//   Gb   @ 1572864  (16384*3072)
// Round-24: r23's store-tolerant waits FIXED. r23 raced at panel ip=1: its
// B(0)/B(1) staging is issued AFTER panel-0's epilogue stores (queue order
// [stores x64, B x4]), so vmcnt(63) retired stores, not B -> MFMA read
// unwritten LDS. For ip>=2 the staging precedes the stores (issued at
// kt=14/15 of the prior panel) and vmcnt(63) is valid. Fix: vmcnt(63) only
// for ip>=2; ip==1 keeps the r22-proven vmcnt(2). Rest = r22 verbatim.
// ---------------------------------------------------------------------------

using f32x4 = __attribute__((ext_vector_type(4))) float;
using s16x8 = __attribute__((ext_vector_type(8))) short;
typedef __attribute__((ext_vector_type(8))) unsigned short u16x8;

#define WB_OFF   0ull
#define GB_OFF   1572864ull

__device__ __forceinline__ void async_load16(const void* g, void* l) {
  __builtin_amdgcn_global_load_lds(
      (const __attribute__((address_space(1))) unsigned int*)g,
      (__attribute__((address_space(3))) unsigned int*)l, 16, 0, 0);
}

__device__ __forceinline__ float bfraw2f(unsigned short u) {
  union { unsigned int i; float f; } c;
  c.i = ((unsigned int)u) << 16;
  return c.f;
}

// -------------------------- fp32 -> bf16 weights only ----------------------
__global__ __launch_bounds__(256) void convert_w_kernel(
    const float* __restrict__ w0, const float* __restrict__ w1,
    const float* __restrict__ w2, const float* __restrict__ w3,
    __hip_bfloat16* __restrict__ dst)
{
  const size_t i = (size_t)blockIdx.x * 256 + threadIdx.x;  // vec4 index
  const float* src;
  __hip_bfloat16* d;
  size_t o;
  if (i < 131072ull)      { src = w0; d = dst;            o = i; }
  else if (i < 262144ull) { src = w1; d = dst + 524288;   o = i - 131072ull; }
  else if (i < 327680ull) { src = w2; d = dst + 1048576;  o = i - 262144ull; }
  else                    { src = w3; d = dst + 1310720;  o = i - 327680ull; }
  const float4 v = *(const float4*)(src + 4 * o);
  __hip_bfloat16 t4[4] = {__float2bfloat16(v.x), __float2bfloat16(v.y),
                          __float2bfloat16(v.z), __float2bfloat16(v.w)};
  *(uint2*)(d + 4 * o) = *(const uint2*)t4;
}

// -------------------------------- GEMM -------------------------------------
// 256 blocks x 512 threads, 1 block/CU. type=bid&1 (0=X,1=H), mband=bid>>1.
// X n-tiles {0,1,2,3,8,9}; H {4,5,6,7,10,11}. W panels L2-resident per XCD.
// LDS: A resident [kt=16][128 rows][64 B] @0 (131072 B); B region @131072:
//   panel 0: block-shared ring-2 (16KB slots); panels 1-5: per-wave private
//   ring-2 (wave w @ +w*4096, 2KB slots of [32 rows][64 B]).
// Swizzle: swz(row)=((row>>1)&3)<<4 on 16B chunks (r7-proven, 0 conflicts).

#define B_BASE 131072

__device__ __forceinline__ void stage_B_shared(const char* base, char* slot,
                                               int koff, int wave, int lane) {
#pragma unroll
  for (int i = 0; i < 2; ++i) {
    const int c = wave * 2 + i;
    const int row  = c * 16 + (lane >> 2);
    const int colb = ((lane & 3) * 16) ^ (((lane >> 3) & 3) << 4);  // pre-swz
    async_load16(base + (size_t)row * 1024 + koff + colb,
                 slot + c * 1024 + lane * 16);
  }
}

__device__ __forceinline__ void cvt_write8(void* dst, const float4& f0,
                                           const float4& f1) {
  union { s16x8 v; __hip_bfloat16 b[8]; } u;
  u.b[0] = __float2bfloat16(f0.x); u.b[1] = __float2bfloat16(f0.y);
  u.b[2] = __float2bfloat16(f0.z); u.b[3] = __float2bfloat16(f0.w);
  u.b[4] = __float2bfloat16(f1.x); u.b[5] = __float2bfloat16(f1.y);
  u.b[6] = __float2bfloat16(f1.z); u.b[7] = __float2bfloat16(f1.w);
  *(s16x8*)dst = u.v;
}

__global__ __launch_bounds__(512, 2) void gemm_kernel(
    const float* __restrict__ xf,
    const float* __restrict__ hf,
    const __hip_bfloat16* __restrict__ Wb,
    __hip_bfloat16* __restrict__ G)
{
  const int bid   = blockIdx.x;     // 256
  const int type  = bid & 1;        // 0 = X, 1 = H
  const int mband = bid >> 1;       // 0..127
  const int m0    = mband * 128;
  const float* Af = (type ? hf : xf) + (size_t)m0 * 512;

  __shared__ __align__(16) char lds[163840];

  const int tid  = threadIdx.x;
  const int lane = tid & 63;
  const int wave = tid >> 6;        // 1x8 wave grid: wave = wn, wm = 0

  const int lk  = (lane >> 4) * 16;
  const int lr  = lane & 15;
  const int rdk = lk ^ (((lr >> 1) & 3) << 4);     // read swizzle (A and B)

  auto rdA = [&](int kt, int fm) {  // fm 0..7, A rows fm*16+lr (wm==0)
    return *(const s16x8*)(lds + kt * 8192 + (fm * 16 + lr) * 64 + rdk);
  };
  auto rdB0 = [&](int slot, int fn) {  // panel-0 block-shared layout
    return *(const s16x8*)(lds + B_BASE + slot * 16384 +
                           (wave * 32 + fn * 16 + lr) * 64 + rdk);
  };

  const int ntl0 = type ? 4 : 0;
  const char* Bb0 = (const char*)Wb + (size_t)ntl0 * 256 * 1024;

  stage_B_shared(Bb0, lds + B_BASE, 0, wave, lane);

  // ---- A streaming setup: LINEAR source, SWIZZLED LDS dest (rule 21) ----
  const int arow = tid >> 2;                         // 0..127
  const int alin = (tid & 3) * 16;                   // linear byte pos
  const int acb  = alin ^ (((arow >> 1) & 3) << 4);  // swizzled LDS pos
  const float* abase = Af + (size_t)arow * 512 + (alin >> 1);
  char* const awr = lds + arow * 64 + acb;           // + kt*8192

  float4 hA, hB;
  {
    const float4 a0 = *(const float4*)(abase);       // A(0)
    const float4 a1 = *(const float4*)(abase + 4);
    hA = *(const float4*)(abase + 32);               // A(1)
    hB = *(const float4*)(abase + 36);
    cvt_write8(awr, a0, a1);                         // write A(0)
  }

  // ---- panel 0: compute ntl0 while streaming A into residence ----
  {
    f32x4 acc[8][2];
#pragma unroll
    for (int a = 0; a < 8; ++a)
#pragma unroll
      for (int b = 0; b < 2; ++b) acc[a][b] = (f32x4){0.f, 0.f, 0.f, 0.f};

#pragma unroll
    for (int kt = 0; kt < 16; ++kt) {
      asm volatile("s_waitcnt vmcnt(0) lgkmcnt(0)" ::: "memory");
      __builtin_amdgcn_s_barrier();   // B(kt)+A(kt+1) retired; A(kt) visible

      if (kt <= 14) cvt_write8(awr + (kt + 1) * 8192, hA, hB);  // A(kt+1)

      const int slot = kt & 1;
      s16x8 b[2], a[8];
#pragma unroll
      for (int fn = 0; fn < 2; ++fn) b[fn] = rdB0(slot, fn);
#pragma unroll
      for (int fm = 0; fm < 8; ++fm) a[fm] = rdA(kt, fm);

      if (kt < 15)
        stage_B_shared(Bb0, lds + B_BASE + ((kt + 1) & 1) * 16384,
                       (kt + 1) * 64, wave, lane);

      if (kt <= 13) {                                 // load A(kt+2)
        hA = *(const float4*)(abase + (kt + 2) * 32);
        hB = *(const float4*)(abase + (kt + 2) * 32 + 4);
      }

      __builtin_amdgcn_s_setprio(1);
#pragma unroll
      for (int fm = 0; fm < 8; ++fm)
#pragma unroll
        for (int fn = 0; fn < 2; ++fn)
          acc[fm][fn] = __builtin_amdgcn_mfma_f32_16x16x32_bf16(
              a[fm], b[fn], acc[fm][fn], 0, 0, 0);
      __builtin_amdgcn_s_setprio(0);
    }

    const int n0 = ntl0 * 256;
    const int mbase = m0 + ((lane >> 4) << 2);
    const int nbase = n0 + wave * 32 + lr;
#pragma unroll
    for (int fm = 0; fm < 8; ++fm)
#pragma unroll
      for (int fn = 0; fn < 2; ++fn)
#pragma unroll
        for (int r = 0; r < 4; ++r)
          G[(size_t)(mbase + fm * 16 + r) * 3072 + nbase + fn * 16] =
              __float2bfloat16(acc[fm][fn][r]);
  }

  // transition: protect B region relayout (shared ring -> private rings)
  __builtin_amdgcn_s_barrier();

  // ---- panels 1..5: barrier-free, per-wave-private B, A reg-dbuf ----
  char* const pB = lds + B_BASE + wave * 4096;   // 2 slots x 2048 B
  const char* const wpriv0 = (const char*)Wb + (size_t)wave * 32768;

  auto rdBp = [&](int slot, int fn) {
    return *(const s16x8*)(pB + slot * 2048 + (fn * 16 + lr) * 64 + rdk);
  };
  auto stage_Bp = [&](int ntl, int kt, int slot) {
    const char* wb = wpriv0 + (size_t)ntl * 262144;
#pragma unroll
    for (int ii = 0; ii < 2; ++ii) {
      const int row  = ii * 16 + (lane >> 2);
      const int colb = ((lane & 3) * 16) ^ (((lane >> 3) & 3) << 4);
      async_load16(wb + (size_t)row * 1024 + kt * 64 + colb,
                   pB + slot * 2048 + ii * 1024 + lane * 16);
    }
  };

  {
    const int ntl1 = type ? 5 : 1;
    stage_Bp(ntl1, 0, 0);
    stage_Bp(ntl1, 1, 1);
  }

  // prefetch A frags for kt=0 (A resident + immutable from here on)
  s16x8 aC[8];
#pragma unroll
  for (int fm = 0; fm < 8; ++fm) aC[fm] = rdA(0, fm);

  for (int ip = 1; ip < 6; ++ip) {
    const int ntl  = (ip < 4) ? (type ? ip + 4 : ip) : (type ? ip + 6 : ip + 4);
    const int ipn  = ip + 1;
    const int ntlN = (ip < 5) ? ((ipn < 4) ? (type ? ipn + 4 : ipn)
                                           : (type ? ipn + 6 : ipn + 4)) : ntl;

    f32x4 acc[8][2];
#pragma unroll
    for (int a = 0; a < 8; ++a)
#pragma unroll
      for (int b = 0; b < 2; ++b) acc[a][b] = (f32x4){0.f, 0.f, 0.f, 0.f};

#pragma unroll
    for (int kt = 0; kt < 16; ++kt) {
      // store-tolerant entry waits, CORRECTED: valid only for ip>=2 where
      // B(0)/B(1) staging precedes the prior panel's epilogue stores in the
      // queue ([B x4, stores]); vmcnt(63) retires the B loads without
      // draining stores. ip==1's staging is issued AFTER panel-0 stores
      // ([stores, B x4]) -> must use vmcnt(2) (drains stores; r22-proven).
      if (ip == 5 && kt == 15)
        asm volatile("s_waitcnt vmcnt(0)" ::: "memory");
      else if (kt <= 1 && ip >= 2)
        asm volatile("s_waitcnt vmcnt(63)" ::: "memory");
      else
        asm volatile("s_waitcnt vmcnt(2)" ::: "memory");

      const int slot = kt & 1;
      s16x8 b[2];
#pragma unroll
      for (int fn = 0; fn < 2; ++fn) b[fn] = rdBp(slot, fn);

      // drain fresh B reads (A prefetches already retired) before slot reuse
      asm volatile("s_waitcnt lgkmcnt(0)" ::: "memory");
      __builtin_amdgcn_sched_barrier(0);   // rule 18
      if (kt <= 13)    stage_Bp(ntl, kt + 2, slot);
      else if (ip < 5) stage_Bp(ntlN, kt - 14, slot);  // parity matches

      __builtin_amdgcn_s_setprio(1);
#pragma unroll
      for (int fm = 0; fm < 4; ++fm)
#pragma unroll
        for (int fn = 0; fn < 2; ++fn)
          acc[fm][fn] = __builtin_amdgcn_mfma_f32_16x16x32_bf16(
              aC[fm], b[fn], acc[fm][fn], 0, 0, 0);

      // prefetch next ktile's A frags under the MFMA shadow; (kt+1)&15
      // wraps to kt0 for the next panel (same A for all panels)
      s16x8 aN[8];
#pragma unroll
      for (int fm = 0; fm < 8; ++fm) aN[fm] = rdA((kt + 1) & 15, fm);

#pragma unroll
      for (int fm = 4; fm < 8; ++fm)
#pragma unroll
        for (int fn = 0; fn < 2; ++fn)
          acc[fm][fn] = __builtin_amdgcn_mfma_f32_16x16x32_bf16(
              aC[fm], b[fn], acc[fm][fn], 0, 0, 0);
      __builtin_amdgcn_s_setprio(0);

#pragma unroll
      for (int q = 0; q < 8; ++q) aC[q] = aN[q];
    }

    const int n0 = ntl * 256;
    const int mbase = m0 + ((lane >> 4) << 2);
    const int nbase = n0 + wave * 32 + lr;
#pragma unroll
    for (int fm = 0; fm < 8; ++fm)
#pragma unroll
      for (int fn = 0; fn < 2; ++fn)
#pragma unroll
        for (int r = 0; r < 4; ++r)
          G[(size_t)(mbase + fm * 16 + r) * 3072 + nbase + fn * 16] =
              __float2bfloat16(acc[fm][fn][r]);
  }
}

// ------------------------------ LN + gates (wave-per-row, r19) -------------
__global__ __launch_bounds__(256) void ln_gate_kernel(
    const __hip_bfloat16* __restrict__ G, const float* __restrict__ h,
    const float* __restrict__ b0, const float* __restrict__ b1,
    const float* __restrict__ b2, const float* __restrict__ b3,
    float* __restrict__ out)
{
  const int w = threadIdx.x >> 6;
  const int L = threadIdx.x & 63;
  const int row = blockIdx.x * 4 + w;
  const unsigned short* g = (const unsigned short*)(G + (size_t)row * 3072);

  __shared__ float zr[4][1024];   // transposed: col c at (c&15)*64 + (c>>4)
  float* const zw = zr[w];

  float v0[16], v1[16];
  {
    const u16x8 a0 = *(const u16x8*)(g + 16 * L);
    const u16x8 a1 = *(const u16x8*)(g + 16 * L + 8);
    const u16x8 c0 = *(const u16x8*)(g + 1024 + 16 * L);
    const u16x8 c1 = *(const u16x8*)(g + 1024 + 16 * L + 8);
#pragma unroll
    for (int q = 0; q < 4; ++q) {
      const float4 f0 = *(const float4*)(b0 + 16 * L + 4 * q);
      const float4 f1 = *(const float4*)(b1 + 16 * L + 4 * q);
      const float bb0[4] = {f0.x, f0.y, f0.z, f0.w};
      const float bb1[4] = {f1.x, f1.y, f1.z, f1.w};
#pragma unroll
      for (int j = 0; j < 4; ++j) {
        const int k = 4 * q + j;
        const unsigned short ua = (k < 8) ? a0[k] : a1[k - 8];
        const unsigned short uc = (k < 8) ? c0[k] : c1[k - 8];
        v0[k] = bfraw2f(ua) + bb0[j];
        v1[k] = bfraw2f(uc) + bb1[j];
      }
    }
  }
  float4 s = make_float4(0.f, 0.f, 0.f, 0.f);
#pragma unroll
  for (int k = 0; k < 16; ++k) {
    s.x += v0[k]; s.y += v0[k] * v0[k];
    s.z += v1[k]; s.w += v1[k] * v1[k];
  }
#pragma unroll
  for (int off = 1; off < 64; off <<= 1) {
    s.x += __shfl_xor(s.x, off);
    s.y += __shfl_xor(s.y, off);
    s.z += __shfl_xor(s.z, off);
    s.w += __shfl_xor(s.w, off);
  }
  const float mu0 = s.x * (1.f / 1024.f);
  const float mu1 = s.z * (1.f / 1024.f);
  const float rs0 = rsqrtf(s.y * (1.f / 1024.f) - mu0 * mu0 + 1e-5f);
  const float rs1 = rsqrtf(s.w * (1.f / 1024.f) - mu1 * mu1 + 1e-5f);

#pragma unroll
  for (int k = 0; k < 16; ++k) {
    const float pre = (v0[k] - mu0) * rs0 + (v1[k] - mu1) * rs1;
    zw[k * 64 + L] = 1.f / (1.f + __expf(-pre));   // c = 16L+k transposed
  }

  float v2[8], v3[8];
  {
    const u16x8 a = *(const u16x8*)(g + 2048 + 8 * L);
    const u16x8 c = *(const u16x8*)(g + 2560 + 8 * L);
#pragma unroll
    for (int q = 0; q < 2; ++q) {
      const float4 f2 = *(const float4*)(b2 + 8 * L + 4 * q);
      const float4 f3 = *(const float4*)(b3 + 8 * L + 4 * q);
      const float bb2[4] = {f2.x, f2.y, f2.z, f2.w};
      const float bb3[4] = {f3.x, f3.y, f3.z, f3.w};
#pragma unroll
      for (int j = 0; j < 4; ++j) {
        const int k = 4 * q + j;
        v2[k] = bfraw2f(a[k]) + bb2[j];
        v3[k] = bfraw2f(c[k]) + bb3[j];
      }
    }
  }
  float4 t = make_float4(0.f, 0.f, 0.f, 0.f);
#pragma unroll
  for (int k = 0; k < 8; ++k) {
    t.x += v2[k]; t.y += v2[k] * v2[k];
    t.z += v3[k]; t.w += v3[k] * v3[k];
  }
#pragma unroll
  for (int off = 1; off < 64; off <<= 1) {
    t.x += __shfl_xor(t.x, off);
    t.y += __shfl_xor(t.y, off);
    t.z += __shfl_xor(t.z, off);
    t.w += __shfl_xor(t.w, off);
  }
  const float mu2 = t.x * (1.f / 512.f);
  const float mu3 = t.z * (1.f / 512.f);
  const float rs2 = rsqrtf(t.y * (1.f / 512.f) - mu2 * mu2 + 1e-5f);
  const float rs3 = rsqrtf(t.w * (1.f / 512.f) - mu3 * mu3 + 1e-5f);

  asm volatile("s_waitcnt lgkmcnt(0)" ::: "memory");  // zw writes done

  const float4 h0 = *(const float4*)(h + (size_t)row * 512 + 8 * L);
  const float4 h1 = *(const float4*)(h + (size_t)row * 512 + 8 * L + 4);
  const float hv[8] = {h0.x, h0.y, h0.z, h0.w, h1.x, h1.y, h1.z, h1.w};

  float o[8];
#pragma unroll
  for (int k = 0; k < 8; ++k) {
    const int c  = 8 * L + k;                         // hat col
    const float z  = zw[(c & 15) * 64 + (c >> 4)];
    const float rr = zw[((512 + c) & 15) * 64 + ((512 + c) >> 4)];
    const float ha  = (v2[k] - mu2) * rs2;
    const float hbv = (v3[k] - mu3) * rs3;
    const float hhat = tanhf(ha + rr * hbv);
    o[k] = (1.f - z) * hv[k] + z * hhat;
  }
  *(float4*)(out + (size_t)row * 512 + 8 * L)     = make_float4(o[0], o[1], o[2], o[3]);
  *(float4*)(out + (size_t)row * 512 + 8 * L + 4) = make_float4(o[4], o[5], o[6], o[7]);
}

// ------------------------------- launcher ----------------------------------
extern "C" void kernel_launch(void* const* d_in, const int* in_sizes, int n_in,
                              void* d_out, int out_size, void* d_ws, size_t ws_size,
                              hipStream_t stream) {
  (void)in_sizes; (void)n_in; (void)out_size; (void)ws_size;
  const float* x      = (const float*)d_in[0];
  const float* h      = (const float*)d_in[1];
  const float* W_i2h  = (const float*)d_in[2];
  const float* b_i2h  = (const float*)d_in[3];
  const float* W_h2h  = (const float*)d_in[4];
  const float* b_h2h  = (const float*)d_in[5];
  const float* W_hatW = (const float*)d_in[6];
  const float* b_hatW = (const float*)d_in[7];
  const float* W_hatU = (const float*)d_in[8];
  const float* b_hatU = (const float*)d_in[9];
  float* out = (float*)d_out;
  __hip_bfloat16* ws = (__hip_bfloat16*)d_ws;

  convert_w_kernel<<<1536, 256, 0, stream>>>(W_i2h, W_h2h, W_hatW, W_hatU,
                                             ws + WB_OFF);
  gemm_kernel<<<256, 512, 0, stream>>>(x, h, ws + WB_OFF, ws + GB_OFF);
  ln_gate_kernel<<<4096, 256, 0, stream>>>(ws + GB_OFF, h, b_i2h, b_h2h,
                                           b_hatW, b_hatU, out);
}